// Round 2
// baseline (282.291 us; speedup 1.0000x reference)
//
#include <hip/hip_runtime.h>
#include <math.h>

#define EMBED 128
#define LDSPAD 136   // 128 + 8 bf16 pad -> 272 B row stride

#define TWO_LOG2E 2.8853900817779268f
#define LOG2E     1.4426950408889634f

typedef __attribute__((ext_vector_type(8))) short short8;
typedef __attribute__((ext_vector_type(4))) float floatx4;
typedef __attribute__((ext_vector_type(4))) unsigned int uint4v;

__device__ __forceinline__ unsigned short f2b(float f) {   // fp32 -> bf16 RNE
    union { float f; unsigned int u; } v; v.f = f;
    unsigned int r = v.u + 0x7FFFu + ((v.u >> 16) & 1u);
    return (unsigned short)(r >> 16);
}

__device__ __forceinline__ float b2f(short u) {
    union { float f; unsigned int i; } v;
    v.i = ((unsigned int)(unsigned short)u) << 16;
    return v.f;
}

// raw v_exp_f32: D = 2^S0. No OCML denormal fixup (exp2f without fast-math
// costs ~5 VALU ops; this is 1). exp2(-inf)=0, exp2(+inf)=inf as needed.
__device__ __forceinline__ float ex2(float x) { return __builtin_amdgcn_exp2f(x); }

// ---------------- K0: cast ent/rel/W to bf16 (rel pre-scaled by 2*log2e) + head histogram ----------------
__global__ __launch_bounds__(256) void k_cast_hist(
    const float* __restrict__ ent, const float* __restrict__ rel, const float* __restrict__ W,
    short* __restrict__ entb, short* __restrict__ relb, short* __restrict__ wb,
    const int* __restrict__ heads, int* __restrict__ cnt,
    int ngE, int ngR, int ngW, int E)
{
    int stride = gridDim.x * 256;
    int total = ngE + ngR + ngW;
    for (int g = blockIdx.x * 256 + threadIdx.x; g < total; g += stride) {
        const float4* src; short* dst; float sc;
        if (g < ngE)            { src = (const float4*)ent + (size_t)g * 2;              dst = entb + (size_t)g * 8;              sc = 1.0f; }
        else if (g < ngE + ngR) { int g2 = g - ngE;       src = (const float4*)rel + (size_t)g2 * 2; dst = relb + (size_t)g2 * 8; sc = TWO_LOG2E; }
        else                    { int g2 = g - ngE - ngR; src = (const float4*)W   + (size_t)g2 * 2; dst = wb   + (size_t)g2 * 8; sc = 1.0f; }
        float4 a = src[0], b = src[1];
        short8 o;
        o[0] = (short)f2b(a.x * sc); o[1] = (short)f2b(a.y * sc);
        o[2] = (short)f2b(a.z * sc); o[3] = (short)f2b(a.w * sc);
        o[4] = (short)f2b(b.x * sc); o[5] = (short)f2b(b.y * sc);
        o[6] = (short)f2b(b.z * sc); o[7] = (short)f2b(b.w * sc);
        *(short8*)dst = o;
    }
    for (int e = blockIdx.x * 256 + threadIdx.x; e < E; e += stride)
        atomicAdd(cnt + heads[e], 1);
}

// ---------------- K1a/b/c: two-level scan (wave-shuffle based) ----------------
__global__ __launch_bounds__(1024) void k_scan1(
    const int* __restrict__ cnt, int* __restrict__ offs,
    int* __restrict__ bsum, int N)
{
    __shared__ int wsum[16];
    const int tid = threadIdx.x;
    int i = blockIdx.x * 1024 + tid;
    int v = (i < N) ? cnt[i] : 0;
    int x = v;
    #pragma unroll
    for (int d = 1; d < 64; d <<= 1) {
        int y = __shfl_up(x, d, 64);
        if ((tid & 63) >= d) x += y;
    }
    if ((tid & 63) == 63) wsum[tid >> 6] = x;
    __syncthreads();
    if (tid < 16) {
        int w = wsum[tid];
        #pragma unroll
        for (int d = 1; d < 16; d <<= 1) {
            int y = __shfl_up(w, d, 16);
            if (tid >= d) w += y;
        }
        wsum[tid] = w;
    }
    __syncthreads();
    int add = (tid >= 64) ? wsum[(tid >> 6) - 1] : 0;
    int incl = x + add;
    if (i < N) offs[i] = incl - v;
    if (tid == 1023) bsum[blockIdx.x] = incl;
}

__global__ __launch_bounds__(1024) void k_scan2(int* __restrict__ bsum, int nb)
{
    __shared__ int wsum[16];
    const int tid = threadIdx.x;
    int v = (tid < nb) ? bsum[tid] : 0;
    int x = v;
    #pragma unroll
    for (int d = 1; d < 64; d <<= 1) {
        int y = __shfl_up(x, d, 64);
        if ((tid & 63) >= d) x += y;
    }
    if ((tid & 63) == 63) wsum[tid >> 6] = x;
    __syncthreads();
    if (tid < 16) {
        int w = wsum[tid];
        #pragma unroll
        for (int d = 1; d < 16; d <<= 1) {
            int y = __shfl_up(w, d, 16);
            if (tid >= d) w += y;
        }
        wsum[tid] = w;
    }
    __syncthreads();
    int add = (tid >= 64) ? wsum[(tid >> 6) - 1] : 0;
    int incl = x + add;
    if (tid < nb) bsum[tid] = incl - v;
}

__global__ __launch_bounds__(256) void k_scan3(
    int* __restrict__ offs, const int* __restrict__ bsum,
    int* __restrict__ cursor, int N)
{
    int i = blockIdx.x * 256 + threadIdx.x;
    if (i < N) {
        int o = offs[i] + bsum[i >> 10];
        offs[i] = o;
        cursor[i] = o;
    }
}

// ---------------- K2: CSR slot-fill: packed (tail, rel) per slot ----------------
__global__ __launch_bounds__(256) void k_csr(
    const int* __restrict__ heads, const int* __restrict__ rels,
    const int* __restrict__ tails, int* __restrict__ cursor,
    int2* __restrict__ tr, int E)
{
    int e = blockIdx.x * 256 + threadIdx.x;
    if (e >= E) return;
    int pos = atomicAdd(cursor + heads[e], 1);
    tr[pos] = make_int2(tails[e], rels[e]);
}

// ---------------- K3: fused score + online-softmax aggregate (log2 domain) ----------------
// 16 lanes per head. relb pre-scaled by 2*log2e; head row scaled at load.
// tanh(h+r) = 1 - 2/(1+exp2(h'+r')).  m, mh stored in log2 domain.
// All exp2 are raw v_exp_f32. Per-block max -> global atomicMax on ordered uint key.
__global__ __launch_bounds__(256) void k_fused(
    const short* __restrict__ entb, const short* __restrict__ relb,
    const int* __restrict__ offs, const int* __restrict__ cnt,
    const int2* __restrict__ tr,
    short* __restrict__ accb, float* __restrict__ mh, float* __restrict__ lh,
    unsigned int* __restrict__ Mbits, int N, int R)
{
    __shared__ short rl[64 * EMBED];   // 16 KB rel table cache (already exp2-scaled)
    const int tid = threadIdx.x;
    if (R <= 64) {
        int nch = R * 16;
        for (int i = tid; i < nch; i += 256)
            ((short8*)rl)[i] = ((const short8*)relb)[i];
    }
    __syncthreads();
    const short* relsrc = (R <= 64) ? (const short*)rl : relb;

    const int lane = tid & 15;
    int head = blockIdx.x * 16 + (tid >> 4);
    float m = -INFINITY;
    if (head < N) {
        int start = offs[head];
        int c     = cnt[head];
        uint4v hu = *((const uint4v*)(entb + (size_t)head * EMBED) + lane);
        float hf[8];
        #pragma unroll
        for (int p = 0; p < 4; ++p) {
            hf[2*p]   = __uint_as_float(hu[p] << 16)          * TWO_LOG2E;
            hf[2*p+1] = __uint_as_float(hu[p] & 0xFFFF0000u)  * TWO_LOG2E;
        }
        float l = 0.f;
        float acc[8] = {0,0,0,0,0,0,0,0};
        for (int base = 0; base < c; base += 16) {
            int rem = c - base;
            int mm  = rem < 16 ? rem : 16;
            int2 trv = make_int2(0, 0);
            if (lane < mm) trv = tr[start + base + lane];
            for (int j = 0; j < mm; ++j) {
                int t = __shfl(trv.x, j, 16);
                int r = __shfl(trv.y, j, 16);
                uint4v vt = *((const uint4v*)(entb + (size_t)t * EMBED) + lane);
                uint4v ru = *((const uint4v*)(relsrc + (size_t)r * EMBED) + lane);
                float S = 0.f;
                float vtf[8];
                #pragma unroll
                for (int p = 0; p < 4; ++p) {
                    unsigned int tu = vt[p], rr = ru[p];
                    float tlo = __uint_as_float(tu << 16);
                    float thi = __uint_as_float(tu & 0xFFFF0000u);
                    float xlo = hf[2*p]   + __uint_as_float(rr << 16);
                    float xhi = hf[2*p+1] + __uint_as_float(rr & 0xFFFF0000u);
                    float elo = ex2(xlo);
                    float ehi = ex2(xhi);
                    float clo = __builtin_amdgcn_rcpf(1.0f + elo);
                    float chi = __builtin_amdgcn_rcpf(1.0f + ehi);
                    S += tlo * (1.0f - 2.0f * clo);
                    S += thi * (1.0f - 2.0f * chi);
                    vtf[2*p]   = tlo;
                    vtf[2*p+1] = thi;
                }
                S += __shfl_xor(S, 1, 16);
                S += __shfl_xor(S, 2, 16);
                S += __shfl_xor(S, 4, 16);
                S += __shfl_xor(S, 8, 16);
                float s2    = S * LOG2E;            // log2-domain score
                float mn    = fmaxf(m, s2);
                float alpha = ex2(m - mn);          // m=-inf first edge -> 0
                float p     = ex2(s2 - mn);
                l = l * alpha + p;
                #pragma unroll
                for (int q = 0; q < 8; ++q)
                    acc[q] = acc[q] * alpha + p * vtf[q];
                m = mn;
            }
        }
        short8 o;
        #pragma unroll
        for (int q = 0; q < 8; ++q) o[q] = (short)f2b(acc[q]);
        *((short8*)(accb + (size_t)head * EMBED) + lane) = o;
        if (lane == 0) { mh[head] = m; lh[head] = l; }
    }
    __shared__ float smax[256];
    smax[tid] = m;
    __syncthreads();
    for (int off = 128; off > 0; off >>= 1) {
        if (tid < off) smax[tid] = fmaxf(smax[tid], smax[tid + off]);
        __syncthreads();
    }
    if (tid == 0) {
        unsigned int u = __float_as_uint(smax[0]);
        unsigned int key = (u & 0x80000000u) ? ~u : (u | 0x80000000u);
        atomicMax(Mbits, key);
    }
}

// ---------------- K4: fused normalize + x = ent + agg + bf16 MFMA GEMM ----------------
// inv = 1/(lh + 1e-10*exp2(M2 - mh2)); out = leaky_relu((ent + acc*inv) @ W^T)
__global__ __launch_bounds__(256) void k_gemm_f(
    const short* __restrict__ entb, const short* __restrict__ accb,
    const float* __restrict__ mh, const float* __restrict__ lh,
    const unsigned int* __restrict__ Mbits, const short* __restrict__ wb,
    float* __restrict__ out, int N)
{
    __shared__ short xs[128 * LDSPAD];
    __shared__ short ws[128 * LDSPAD];
    const int tid = threadIdx.x;
    const int n0  = blockIdx.x * 128;
    unsigned int k = Mbits[0];
    const float M2 = (k & 0x80000000u) ? __uint_as_float(k & 0x7FFFFFFFu)
                                       : __uint_as_float(~k);

    // stage W (pre-cast bf16): 2048 short8 chunks, 8 per thread
    #pragma unroll
    for (int it = 0; it < 8; ++it) {
        int ch = it * 256 + tid;
        int row = ch >> 4, col8 = ch & 15;
        *(short8*)(ws + row * LDSPAD + col8 * 8) = ((const short8*)wb)[ch];
    }
    // stage x = ent + acc*inv: 2048 short8 chunks, 8 per thread
    #pragma unroll
    for (int it = 0; it < 8; ++it) {
        int ch = it * 256 + tid;
        int row = ch >> 4, col8 = ch & 15;
        int g = n0 + row;
        short8 v = {0,0,0,0,0,0,0,0};
        if (g < N) {
            float inv = 1.0f / (lh[g] + 1e-10f * ex2(M2 - mh[g]));  // inf -> 0 (degenerate head)
            short8 e8 = *((const short8*)(entb + (size_t)g * EMBED) + col8);
            short8 a8 = *((const short8*)(accb + (size_t)g * EMBED) + col8);
            #pragma unroll
            for (int q = 0; q < 8; ++q)
                v[q] = (short)f2b(b2f(e8[q]) + b2f(a8[q]) * inv);
        }
        *(short8*)(xs + row * LDSPAD + col8 * 8) = v;
    }
    __syncthreads();

    const int wv   = tid >> 6;
    const int lane = tid & 63;
    const int n16  = lane & 15;
    const int quad = lane >> 4;

    floatx4 acc[2][8];
    #pragma unroll
    for (int rt = 0; rt < 2; ++rt)
        #pragma unroll
        for (int jt = 0; jt < 8; ++jt)
            acc[rt][jt] = (floatx4){0.f, 0.f, 0.f, 0.f};

    #pragma unroll
    for (int kc = 0; kc < 4; ++kc) {
        int koff = kc * 32 + quad * 8;
        short8 a0 = *(const short8*)(xs + (wv * 32      + n16) * LDSPAD + koff);
        short8 a1 = *(const short8*)(xs + (wv * 32 + 16 + n16) * LDSPAD + koff);
        #pragma unroll
        for (int jt = 0; jt < 8; ++jt) {
            short8 b = *(const short8*)(ws + (jt * 16 + n16) * LDSPAD + koff);
            acc[0][jt] = __builtin_amdgcn_mfma_f32_16x16x32_bf16(a0, b, acc[0][jt], 0, 0, 0);
            acc[1][jt] = __builtin_amdgcn_mfma_f32_16x16x32_bf16(a1, b, acc[1][jt], 0, 0, 0);
        }
    }

    #pragma unroll
    for (int rt = 0; rt < 2; ++rt) {
        int rowbase = n0 + wv * 32 + rt * 16 + quad * 4;
        #pragma unroll
        for (int r = 0; r < 4; ++r) {
            int grow = rowbase + r;
            if (grow < N) {
                float* o = out + (size_t)grow * EMBED + n16;
                #pragma unroll
                for (int jt = 0; jt < 8; ++jt) {
                    float v = acc[rt][jt][r];
                    o[jt * 16] = (v > 0.f) ? v : 0.2f * v;
                }
            }
        }
    }
}

extern "C" void kernel_launch(void* const* d_in, const int* in_sizes, int n_in,
                              void* d_out, int out_size, void* d_ws, size_t ws_size,
                              hipStream_t stream)
{
    const float* ent   = (const float*)d_in[0];   // entity_emb  [N,128] fp32
    const float* rel   = (const float*)d_in[1];   // rel_embed   [R,128] fp32
    const float* W     = (const float*)d_in[2];   // W           [128,128] fp32
    const int*   heads = (const int*)d_in[3];
    const int*   rels  = (const int*)d_in[4];
    const int*   tails = (const int*)d_in[5];
    const int E = in_sizes[3];
    const int N = in_sizes[0] / EMBED;
    const int R = in_sizes[1] / EMBED;
    float* out = (float*)d_out;

    // ws layout:
    // accb[N*128]s | mh[N]f | lh[N]f | tr[E]int2 | cnt[N]i | offs[N]i | cursor[N]i |
    // wb[16384]s (32KB) | bsum[1024]i | Mbits[4]u | entb[N*128]s | relb[R*128]s
    short* accb        = (short*)d_ws;
    float* mh          = (float*)(accb + (size_t)N * EMBED);
    float* lh          = mh + N;
    int2*  tr          = (int2*)(lh + N);
    int*   cnt         = (int*)(tr + E);
    int*   offs        = cnt + N;
    int*   cursor      = offs + N;
    short* wb          = (short*)(cursor + N);          // 128*128 bf16 = 32 KB
    int*   bsum        = (int*)(wb + 16384);            // 1024 ints
    unsigned int* Mbits = (unsigned int*)(bsum + 1024); // 16 B slot (alignment pad)
    short* entb        = (short*)(Mbits + 4);
    short* relb        = entb + (size_t)N * EMBED;

    const int nb  = (N + 1023) >> 10;       // scan blocks
    const int ngh = (N + 15) / 16;          // per-head group blocks

    hipMemsetAsync(cnt, 0, (size_t)N * sizeof(int), stream);
    hipMemsetAsync((void*)Mbits, 0, sizeof(unsigned int), stream);

    int ngE = N * EMBED / 8, ngR = R * EMBED / 8, ngW = EMBED * EMBED / 8;
    k_cast_hist<<<2048, 256, 0, stream>>>(ent, rel, W, entb, relb, wb, heads, cnt, ngE, ngR, ngW, E);
    k_scan1<<<nb, 1024, 0, stream>>>(cnt, offs, bsum, N);
    k_scan2<<<1, 1024, 0, stream>>>(bsum, nb);
    k_scan3<<<(N + 255) / 256, 256, 0, stream>>>(offs, bsum, cursor, N);
    k_csr<<<(E + 255) / 256, 256, 0, stream>>>(heads, rels, tails, cursor, tr, E);
    k_fused<<<ngh, 256, 0, stream>>>(entb, relb, offs, cnt, tr, accb, mh, lh, Mbits, N, R);
    k_gemm_f<<<(N + 127) / 128, 256, 0, stream>>>(entb, accb, mh, lh, Mbits, wb, out, N);
}

// Round 3
// 252.304 us; speedup vs baseline: 1.1189x; 1.1189x over previous
//
#include <hip/hip_runtime.h>
#include <math.h>

#define EMBED 128
#define BMAX 8192    // blockmax array (fused grid = ceil(N/16) = 6250 <= BMAX)
#define LDSPAD 136   // 128 + 8 bf16 pad -> 272 B row stride

#define TWO_LOG2E 2.8853900817779268f

typedef __attribute__((ext_vector_type(8))) short short8;
typedef __attribute__((ext_vector_type(4))) float floatx4;

__device__ __forceinline__ float ex2(float x) { return __builtin_amdgcn_exp2f(x); }

__device__ __forceinline__ float fast_tanh2(float x) {     // 1 mul + 1 exp + 1 rcp
    float e = ex2(TWO_LOG2E * x);                           // x<<0 -> 0 -> -1; x>>0 -> inf -> 1
    return 1.0f - 2.0f * __builtin_amdgcn_rcpf(1.0f + e);
}

__device__ __forceinline__ unsigned short f2b(float f) {   // fp32 -> bf16 RNE
    union { float f; unsigned int u; } v; v.f = f;
    unsigned int r = v.u + 0x7FFFu + ((v.u >> 16) & 1u);
    return (unsigned short)(r >> 16);
}

__device__ __forceinline__ float b2f(short u) {
    union { float f; unsigned int i; } v;
    v.i = ((unsigned int)(unsigned short)u) << 16;
    return v.f;
}

// ---------------- K0: cast ent/rel/W to bf16 + head histogram ----------------
__global__ __launch_bounds__(256) void k_cast_hist(
    const float* __restrict__ ent, const float* __restrict__ rel, const float* __restrict__ W,
    short* __restrict__ entb, short* __restrict__ relb, short* __restrict__ wb,
    const int* __restrict__ heads, int* __restrict__ cnt,
    int ngE, int ngR, int ngW, int E)
{
    int stride = gridDim.x * 256;
    int total = ngE + ngR + ngW;
    for (int g = blockIdx.x * 256 + threadIdx.x; g < total; g += stride) {
        const float4* src; short* dst;
        if (g < ngE)            { src = (const float4*)ent + (size_t)g * 2;              dst = entb + (size_t)g * 8; }
        else if (g < ngE + ngR) { int g2 = g - ngE;       src = (const float4*)rel + (size_t)g2 * 2; dst = relb + (size_t)g2 * 8; }
        else                    { int g2 = g - ngE - ngR; src = (const float4*)W   + (size_t)g2 * 2; dst = wb   + (size_t)g2 * 8; }
        float4 a = src[0], b = src[1];
        short8 o;
        o[0] = (short)f2b(a.x); o[1] = (short)f2b(a.y); o[2] = (short)f2b(a.z); o[3] = (short)f2b(a.w);
        o[4] = (short)f2b(b.x); o[5] = (short)f2b(b.y); o[6] = (short)f2b(b.z); o[7] = (short)f2b(b.w);
        *(short8*)dst = o;
    }
    for (int e = blockIdx.x * 256 + threadIdx.x; e < E; e += stride)
        atomicAdd(cnt + heads[e], 1);
}

// ---------------- K1a/b/c: two-level scan (wave-shuffle based) ----------------
__global__ __launch_bounds__(1024) void k_scan1(
    const int* __restrict__ cnt, int* __restrict__ offs,
    int* __restrict__ bsum, int N)
{
    __shared__ int wsum[16];
    const int tid = threadIdx.x;
    int i = blockIdx.x * 1024 + tid;
    int v = (i < N) ? cnt[i] : 0;
    int x = v;
    #pragma unroll
    for (int d = 1; d < 64; d <<= 1) {
        int y = __shfl_up(x, d, 64);
        if ((tid & 63) >= d) x += y;
    }
    if ((tid & 63) == 63) wsum[tid >> 6] = x;
    __syncthreads();
    if (tid < 16) {
        int w = wsum[tid];
        #pragma unroll
        for (int d = 1; d < 16; d <<= 1) {
            int y = __shfl_up(w, d, 16);
            if (tid >= d) w += y;
        }
        wsum[tid] = w;
    }
    __syncthreads();
    int add = (tid >= 64) ? wsum[(tid >> 6) - 1] : 0;
    int incl = x + add;
    if (i < N) offs[i] = incl - v;
    if (tid == 1023) bsum[blockIdx.x] = incl;
}

__global__ __launch_bounds__(1024) void k_scan2(int* __restrict__ bsum, int nb)
{
    __shared__ int wsum[16];
    const int tid = threadIdx.x;
    int v = (tid < nb) ? bsum[tid] : 0;
    int x = v;
    #pragma unroll
    for (int d = 1; d < 64; d <<= 1) {
        int y = __shfl_up(x, d, 64);
        if ((tid & 63) >= d) x += y;
    }
    if ((tid & 63) == 63) wsum[tid >> 6] = x;
    __syncthreads();
    if (tid < 16) {
        int w = wsum[tid];
        #pragma unroll
        for (int d = 1; d < 16; d <<= 1) {
            int y = __shfl_up(w, d, 16);
            if (tid >= d) w += y;
        }
        wsum[tid] = w;
    }
    __syncthreads();
    int add = (tid >= 64) ? wsum[(tid >> 6) - 1] : 0;
    int incl = x + add;
    if (tid < nb) bsum[tid] = incl - v;
}

__global__ __launch_bounds__(256) void k_scan3(
    int* __restrict__ offs, const int* __restrict__ bsum,
    int* __restrict__ cursor, int N)
{
    int i = blockIdx.x * 256 + threadIdx.x;
    if (i < N) {
        int o = offs[i] + bsum[i >> 10];
        offs[i] = o;
        cursor[i] = o;
    }
}

// ---------------- K2: CSR slot-fill: packed (tail, rel) per slot ----------------
__global__ __launch_bounds__(256) void k_csr(
    const int* __restrict__ heads, const int* __restrict__ rels,
    const int* __restrict__ tails, int* __restrict__ cursor,
    int2* __restrict__ tr, int E)
{
    int e = blockIdx.x * 256 + threadIdx.x;
    if (e >= E) return;
    int pos = atomicAdd(cursor + heads[e], 1);
    tr[pos] = make_int2(tails[e], rels[e]);
}

// ---------------- K3: fused score + online-softmax aggregate ----------------
// 16 lanes per head. One tail-row gather serves both the tanh-dot and the
// weighted accumulate. Writes acc (bf16, unnormalized), per-head (m, l), blockmax.
// Identical to the verified 70 us schedule; only fast_tanh2 internals changed
// (__expf(2x) -> ex2(TWO_LOG2E*x), one v_mul less per element).
__global__ __launch_bounds__(256) void k_fused(
    const short* __restrict__ entb, const short* __restrict__ relb,
    const int* __restrict__ offs, const int* __restrict__ cnt,
    const int2* __restrict__ tr,
    short* __restrict__ accb, float* __restrict__ mh, float* __restrict__ lh,
    float* __restrict__ blockmax, int N, int R)
{
    __shared__ short rl[64 * EMBED];   // 16 KB rel table cache
    const int tid = threadIdx.x;
    if (R <= 64) {
        int nch = R * 16;
        for (int i = tid; i < nch; i += 256)
            ((short8*)rl)[i] = ((const short8*)relb)[i];
    }
    __syncthreads();
    const short* relsrc = (R <= 64) ? (const short*)rl : relb;

    const int lane = tid & 15;
    int head = blockIdx.x * 16 + (tid >> 4);
    float m = -INFINITY;
    if (head < N) {
        int start = offs[head];
        int c     = cnt[head];
        short8 hh = *((const short8*)(entb + (size_t)head * EMBED) + lane);
        float hf[8];
        #pragma unroll
        for (int i = 0; i < 8; ++i) hf[i] = b2f(hh[i]);
        float l = 0.f;
        float acc[8] = {0,0,0,0,0,0,0,0};
        for (int base = 0; base < c; base += 16) {
            int rem = c - base;
            int mm  = rem < 16 ? rem : 16;
            int2 trv = make_int2(0, 0);
            if (lane < mm) trv = tr[start + base + lane];
            for (int j = 0; j < mm; ++j) {
                int t = __shfl(trv.x, j, 16);
                int r = __shfl(trv.y, j, 16);
                short8 vt = *((const short8*)(entb + (size_t)t * EMBED) + lane);
                short8 vr = *((const short8*)(relsrc + (size_t)r * EMBED) + lane);
                float s = 0.f;
                #pragma unroll
                for (int i = 0; i < 8; ++i)
                    s += b2f(vt[i]) * fast_tanh2(hf[i] + b2f(vr[i]));
                s += __shfl_xor(s, 1, 16);
                s += __shfl_xor(s, 2, 16);
                s += __shfl_xor(s, 4, 16);
                s += __shfl_xor(s, 8, 16);
                float mn    = fmaxf(m, s);
                float alpha = __expf(m - mn);     // m=-inf first edge -> 0
                float p     = __expf(s - mn);
                l = l * alpha + p;
                #pragma unroll
                for (int q = 0; q < 8; ++q)
                    acc[q] = acc[q] * alpha + p * b2f(vt[q]);
                m = mn;
            }
        }
        short8 o;
        #pragma unroll
        for (int q = 0; q < 8; ++q) o[q] = (short)f2b(acc[q]);
        *((short8*)(accb + (size_t)head * EMBED) + lane) = o;
        if (lane == 0) { mh[head] = m; lh[head] = l; }
    }
    __shared__ float smax[256];
    smax[tid] = m;
    __syncthreads();
    for (int off = 128; off > 0; off >>= 1) {
        if (tid < off) smax[tid] = fmaxf(smax[tid], smax[tid + off]);
        __syncthreads();
    }
    if (tid == 0) blockmax[blockIdx.x] = smax[0];
}

// ---------------- K3b: reduce blockmax -> M ----------------
__global__ __launch_bounds__(256) void k_maxred(
    const float* __restrict__ blockmax, float* __restrict__ Mout, int n)
{
    __shared__ float smax[256];
    float m = -INFINITY;
    for (int i = threadIdx.x; i < n; i += 256) m = fmaxf(m, blockmax[i]);
    smax[threadIdx.x] = m;
    __syncthreads();
    for (int off = 128; off > 0; off >>= 1) {
        if ((int)threadIdx.x < off)
            smax[threadIdx.x] = fmaxf(smax[threadIdx.x], smax[threadIdx.x + off]);
        __syncthreads();
    }
    if (threadIdx.x == 0) Mout[0] = smax[0];
}

// ---------------- K4: fused normalize + x = ent + agg + bf16 MFMA GEMM ----------------
// x[g] = entb[g] + accb[g] / (lh[g] + 1e-10*exp(M - mh[g])); out = leaky_relu(x @ W^T).
__global__ __launch_bounds__(256) void k_gemm_f(
    const short* __restrict__ entb, const short* __restrict__ accb,
    const float* __restrict__ mh, const float* __restrict__ lh,
    const float* __restrict__ Mptr, const short* __restrict__ wb,
    float* __restrict__ out, int N)
{
    __shared__ short xs[128 * LDSPAD];
    __shared__ short ws[128 * LDSPAD];
    const int tid = threadIdx.x;
    const int n0  = blockIdx.x * 128;
    const float M = Mptr[0];

    // stage W (pre-cast bf16): 2048 short8 chunks, 8 per thread
    #pragma unroll
    for (int it = 0; it < 8; ++it) {
        int ch = it * 256 + tid;
        int row = ch >> 4, col8 = ch & 15;
        *(short8*)(ws + row * LDSPAD + col8 * 8) = ((const short8*)wb)[ch];
    }
    // stage x = ent + acc*inv: 2048 short8 chunks, 8 per thread
    #pragma unroll
    for (int it = 0; it < 8; ++it) {
        int ch = it * 256 + tid;
        int row = ch >> 4, col8 = ch & 15;
        int g = n0 + row;
        short8 v = {0,0,0,0,0,0,0,0};
        if (g < N) {
            float inv = 1.0f / (lh[g] + 1e-10f * __expf(M - mh[g]));  // inf -> 0 (degenerate head)
            short8 e8 = *((const short8*)(entb + (size_t)g * EMBED) + col8);
            short8 a8 = *((const short8*)(accb + (size_t)g * EMBED) + col8);
            #pragma unroll
            for (int q = 0; q < 8; ++q)
                v[q] = (short)f2b(b2f(e8[q]) + b2f(a8[q]) * inv);
        }
        *(short8*)(xs + row * LDSPAD + col8 * 8) = v;
    }
    __syncthreads();

    const int wv   = tid >> 6;
    const int lane = tid & 63;
    const int n16  = lane & 15;
    const int quad = lane >> 4;

    floatx4 acc[2][8];
    #pragma unroll
    for (int rt = 0; rt < 2; ++rt)
        #pragma unroll
        for (int jt = 0; jt < 8; ++jt)
            acc[rt][jt] = (floatx4){0.f, 0.f, 0.f, 0.f};

    #pragma unroll
    for (int kc = 0; kc < 4; ++kc) {
        int koff = kc * 32 + quad * 8;
        short8 a0 = *(const short8*)(xs + (wv * 32      + n16) * LDSPAD + koff);
        short8 a1 = *(const short8*)(xs + (wv * 32 + 16 + n16) * LDSPAD + koff);
        #pragma unroll
        for (int jt = 0; jt < 8; ++jt) {
            short8 b = *(const short8*)(ws + (jt * 16 + n16) * LDSPAD + koff);
            acc[0][jt] = __builtin_amdgcn_mfma_f32_16x16x32_bf16(a0, b, acc[0][jt], 0, 0, 0);
            acc[1][jt] = __builtin_amdgcn_mfma_f32_16x16x32_bf16(a1, b, acc[1][jt], 0, 0, 0);
        }
    }

    #pragma unroll
    for (int rt = 0; rt < 2; ++rt) {
        int rowbase = n0 + wv * 32 + rt * 16 + quad * 4;
        #pragma unroll
        for (int r = 0; r < 4; ++r) {
            int grow = rowbase + r;
            if (grow < N) {
                float* o = out + (size_t)grow * EMBED + n16;
                #pragma unroll
                for (int jt = 0; jt < 8; ++jt) {
                    float v = acc[rt][jt][r];
                    o[jt * 16] = (v > 0.f) ? v : 0.2f * v;
                }
            }
        }
    }
}

extern "C" void kernel_launch(void* const* d_in, const int* in_sizes, int n_in,
                              void* d_out, int out_size, void* d_ws, size_t ws_size,
                              hipStream_t stream)
{
    const float* ent   = (const float*)d_in[0];   // entity_emb  [N,128] fp32
    const float* rel   = (const float*)d_in[1];   // rel_embed   [R,128] fp32
    const float* W     = (const float*)d_in[2];   // W           [128,128] fp32
    const int*   heads = (const int*)d_in[3];
    const int*   rels  = (const int*)d_in[4];
    const int*   tails = (const int*)d_in[5];
    const int E = in_sizes[3];
    const int N = in_sizes[0] / EMBED;
    const int R = in_sizes[1] / EMBED;
    float* out = (float*)d_out;

    // ws layout:
    // accb[N*128]s | mh[N]f | lh[N]f | tr[E]int2 | cnt[N]i | offs[N]i | cursor[N]i |
    // blockmax[BMAX]f | Mval[4]f | bsum[1024]i | wb[16384]s | entb[N*128]s | relb[R*128]s
    short* accb     = (short*)d_ws;
    float* mh       = (float*)(accb + (size_t)N * EMBED);
    float* lh       = mh + N;
    int2*  tr       = (int2*)(lh + N);
    int*   cnt      = (int*)(tr + E);
    int*   offs     = cnt + N;
    int*   cursor   = offs + N;
    float* blockmax = (float*)(cursor + N);
    float* Mval     = blockmax + BMAX;
    int*   bsum     = (int*)(Mval + 4);             // 16 B slot keeps alignment
    short* wb       = (short*)(bsum + 1024);        // 128*128 bf16 = 32 KB
    short* entb     = wb + 16384;
    short* relb     = entb + (size_t)N * EMBED;

    const int nb  = (N + 1023) >> 10;       // scan blocks
    const int ngh = (N + 15) / 16;          // per-head group blocks

    hipMemsetAsync(cnt, 0, (size_t)N * sizeof(int), stream);

    int ngE = N * EMBED / 8, ngR = R * EMBED / 8, ngW = EMBED * EMBED / 8;
    k_cast_hist<<<2048, 256, 0, stream>>>(ent, rel, W, entb, relb, wb, heads, cnt, ngE, ngR, ngW, E);
    k_scan1<<<nb, 1024, 0, stream>>>(cnt, offs, bsum, N);
    k_scan2<<<1, 1024, 0, stream>>>(bsum, nb);
    k_scan3<<<(N + 255) / 256, 256, 0, stream>>>(offs, bsum, cursor, N);
    k_csr<<<(E + 255) / 256, 256, 0, stream>>>(heads, rels, tails, cursor, tr, E);
    k_fused<<<ngh, 256, 0, stream>>>(entb, relb, offs, cnt, tr, accb, mh, lh, blockmax, N, R);
    k_maxred<<<1, 256, 0, stream>>>(blockmax, Mval, ngh);
    k_gemm_f<<<(N + 127) / 128, 256, 0, stream>>>(entb, accb, mh, lh, Mval, wb, out, N);
}

// Round 4
// 250.770 us; speedup vs baseline: 1.1257x; 1.0061x over previous
//
#include <hip/hip_runtime.h>
#include <math.h>

#define EMBED 128
#define BMAX 8192    // blockmax array (fused grid = ceil(N/16) = 6250 <= BMAX)
#define LDSPAD 136   // 128 + 8 bf16 pad -> 272 B row stride
#define DBINS 64     // degree bins for counting sort (deg clamped to 63)

#define TWO_LOG2E 2.8853900817779268f

typedef __attribute__((ext_vector_type(8))) short short8;
typedef __attribute__((ext_vector_type(4))) float floatx4;

__device__ __forceinline__ float ex2(float x) { return __builtin_amdgcn_exp2f(x); }

__device__ __forceinline__ float fast_tanh2(float x) {     // 1 mul + 1 exp + 1 rcp
    float e = ex2(TWO_LOG2E * x);                           // x<<0 -> 0 -> -1; x>>0 -> inf -> 1
    return 1.0f - 2.0f * __builtin_amdgcn_rcpf(1.0f + e);
}

__device__ __forceinline__ unsigned short f2b(float f) {   // fp32 -> bf16 RNE
    union { float f; unsigned int u; } v; v.f = f;
    unsigned int r = v.u + 0x7FFFu + ((v.u >> 16) & 1u);
    return (unsigned short)(r >> 16);
}

__device__ __forceinline__ float b2f(short u) {
    union { float f; unsigned int i; } v;
    v.i = ((unsigned int)(unsigned short)u) << 16;
    return v.f;
}

// ---------------- K0: cast ent/rel/W to bf16 + head histogram (+ zero ghist) ----------------
__global__ __launch_bounds__(256) void k_cast_hist(
    const float* __restrict__ ent, const float* __restrict__ rel, const float* __restrict__ W,
    short* __restrict__ entb, short* __restrict__ relb, short* __restrict__ wb,
    const int* __restrict__ heads, int* __restrict__ cnt, int* __restrict__ ghist,
    int ngE, int ngR, int ngW, int E)
{
    if (blockIdx.x == 0 && threadIdx.x < DBINS) ghist[threadIdx.x] = 0;  // no reader until k_scan1
    int stride = gridDim.x * 256;
    int total = ngE + ngR + ngW;
    for (int g = blockIdx.x * 256 + threadIdx.x; g < total; g += stride) {
        const float4* src; short* dst;
        if (g < ngE)            { src = (const float4*)ent + (size_t)g * 2;              dst = entb + (size_t)g * 8; }
        else if (g < ngE + ngR) { int g2 = g - ngE;       src = (const float4*)rel + (size_t)g2 * 2; dst = relb + (size_t)g2 * 8; }
        else                    { int g2 = g - ngE - ngR; src = (const float4*)W   + (size_t)g2 * 2; dst = wb   + (size_t)g2 * 8; }
        float4 a = src[0], b = src[1];
        short8 o;
        o[0] = (short)f2b(a.x); o[1] = (short)f2b(a.y); o[2] = (short)f2b(a.z); o[3] = (short)f2b(a.w);
        o[4] = (short)f2b(b.x); o[5] = (short)f2b(b.y); o[6] = (short)f2b(b.z); o[7] = (short)f2b(b.w);
        *(short8*)dst = o;
    }
    for (int e = blockIdx.x * 256 + threadIdx.x; e < E; e += stride)
        atomicAdd(cnt + heads[e], 1);
}

// ---------------- K1a: block scan of cnt + degree histogram ----------------
__global__ __launch_bounds__(1024) void k_scan1(
    const int* __restrict__ cnt, int* __restrict__ offs,
    int* __restrict__ bsum, int* __restrict__ ghist, int N)
{
    __shared__ int wsum[16];
    __shared__ int dh[DBINS];
    const int tid = threadIdx.x;
    if (tid < DBINS) dh[tid] = 0;
    int i = blockIdx.x * 1024 + tid;
    int v = (i < N) ? cnt[i] : 0;
    __syncthreads();
    if (i < N) atomicAdd(&dh[v < DBINS ? v : DBINS - 1], 1);
    int x = v;
    #pragma unroll
    for (int d = 1; d < 64; d <<= 1) {
        int y = __shfl_up(x, d, 64);
        if ((tid & 63) >= d) x += y;
    }
    if ((tid & 63) == 63) wsum[tid >> 6] = x;
    __syncthreads();
    if (tid < 16) {
        int w = wsum[tid];
        #pragma unroll
        for (int d = 1; d < 16; d <<= 1) {
            int y = __shfl_up(w, d, 16);
            if (tid >= d) w += y;
        }
        wsum[tid] = w;
    }
    __syncthreads();
    int add = (tid >= 64) ? wsum[(tid >> 6) - 1] : 0;
    int incl = x + add;
    if (i < N) offs[i] = incl - v;
    if (tid == 1023) bsum[blockIdx.x] = incl;
    if (tid < DBINS && dh[tid] > 0) atomicAdd(ghist + tid, dh[tid]);
}

// ---------------- K1b: scan block sums + exclusive-scan degree histogram ----------------
__global__ __launch_bounds__(1024) void k_scan2(
    int* __restrict__ bsum, int* __restrict__ ghist, int* __restrict__ dbase, int nb)
{
    __shared__ int wsum[16];
    const int tid = threadIdx.x;
    int v = (tid < nb) ? bsum[tid] : 0;
    int x = v;
    #pragma unroll
    for (int d = 1; d < 64; d <<= 1) {
        int y = __shfl_up(x, d, 64);
        if ((tid & 63) >= d) x += y;
    }
    if ((tid & 63) == 63) wsum[tid >> 6] = x;
    __syncthreads();
    if (tid < 16) {
        int w = wsum[tid];
        #pragma unroll
        for (int d = 1; d < 16; d <<= 1) {
            int y = __shfl_up(w, d, 16);
            if (tid >= d) w += y;
        }
        wsum[tid] = w;
    }
    __syncthreads();
    int add = (tid >= 64) ? wsum[(tid >> 6) - 1] : 0;
    int incl = x + add;
    if (tid < nb) bsum[tid] = incl - v;
    // exclusive scan of 64-bin degree histogram (lanes 0..63 of wave 0)
    if (tid < DBINS) {
        int g = ghist[tid];
        int s = g;
        #pragma unroll
        for (int d = 1; d < 64; d <<= 1) {
            int y = __shfl_up(s, d, 64);
            if (tid >= d) s += y;
        }
        dbase[tid] = s - g;
    }
}

// ---------------- K1c: finalize offs/cursor + counting-sort scatter of head ids ----------------
__global__ __launch_bounds__(256) void k_scan3(
    int* __restrict__ offs, const int* __restrict__ bsum,
    int* __restrict__ cursor, const int* __restrict__ cnt,
    int* __restrict__ dbase, int* __restrict__ order, int N)
{
    __shared__ int lcnt[DBINS];
    __shared__ int lbase[DBINS];
    const int tid = threadIdx.x;
    if (tid < DBINS) lcnt[tid] = 0;
    __syncthreads();
    int i = blockIdx.x * 256 + tid;
    int deg = 0, lrank = 0;
    if (i < N) {
        int o = offs[i] + bsum[i >> 10];
        offs[i] = o;
        cursor[i] = o;
        int c = cnt[i];
        deg = c < DBINS ? c : DBINS - 1;
        lrank = atomicAdd(&lcnt[deg], 1);          // LDS atomic: local rank within block
    }
    __syncthreads();
    if (tid < DBINS) {
        int n = lcnt[tid];
        lbase[tid] = n > 0 ? atomicAdd(dbase + tid, n) : 0;   // reserve global range per bin
    }
    __syncthreads();
    if (i < N) order[lbase[deg] + lrank] = i;
}

// ---------------- K2: CSR slot-fill: packed (tail, rel) per slot ----------------
__global__ __launch_bounds__(256) void k_csr(
    const int* __restrict__ heads, const int* __restrict__ rels,
    const int* __restrict__ tails, int* __restrict__ cursor,
    int2* __restrict__ tr, int E)
{
    int e = blockIdx.x * 256 + threadIdx.x;
    if (e >= E) return;
    int pos = atomicAdd(cursor + heads[e], 1);
    tr[pos] = make_int2(tails[e], rels[e]);
}

// ---------------- K3: fused score + online-softmax aggregate ----------------
// 16 lanes per head; heads processed in degree-sorted order (order[] is a
// permutation -> results identical, wave divergence minimized).
// Loop body byte-identical to the verified 66 us schedule.
__global__ __launch_bounds__(256) void k_fused(
    const short* __restrict__ entb, const short* __restrict__ relb,
    const int* __restrict__ offs, const int* __restrict__ cnt,
    const int2* __restrict__ tr, const int* __restrict__ order,
    short* __restrict__ accb, float* __restrict__ mh, float* __restrict__ lh,
    float* __restrict__ blockmax, int N, int R)
{
    __shared__ short rl[64 * EMBED];   // 16 KB rel table cache
    const int tid = threadIdx.x;
    if (R <= 64) {
        int nch = R * 16;
        for (int i = tid; i < nch; i += 256)
            ((short8*)rl)[i] = ((const short8*)relb)[i];
    }
    __syncthreads();
    const short* relsrc = (R <= 64) ? (const short*)rl : relb;

    const int lane = tid & 15;
    int head0 = blockIdx.x * 16 + (tid >> 4);
    int head  = (head0 < N) ? order[head0] : N;
    float m = -INFINITY;
    if (head < N) {
        int start = offs[head];
        int c     = cnt[head];
        short8 hh = *((const short8*)(entb + (size_t)head * EMBED) + lane);
        float hf[8];
        #pragma unroll
        for (int i = 0; i < 8; ++i) hf[i] = b2f(hh[i]);
        float l = 0.f;
        float acc[8] = {0,0,0,0,0,0,0,0};
        for (int base = 0; base < c; base += 16) {
            int rem = c - base;
            int mm  = rem < 16 ? rem : 16;
            int2 trv = make_int2(0, 0);
            if (lane < mm) trv = tr[start + base + lane];
            for (int j = 0; j < mm; ++j) {
                int t = __shfl(trv.x, j, 16);
                int r = __shfl(trv.y, j, 16);
                short8 vt = *((const short8*)(entb + (size_t)t * EMBED) + lane);
                short8 vr = *((const short8*)(relsrc + (size_t)r * EMBED) + lane);
                float s = 0.f;
                #pragma unroll
                for (int i = 0; i < 8; ++i)
                    s += b2f(vt[i]) * fast_tanh2(hf[i] + b2f(vr[i]));
                s += __shfl_xor(s, 1, 16);
                s += __shfl_xor(s, 2, 16);
                s += __shfl_xor(s, 4, 16);
                s += __shfl_xor(s, 8, 16);
                float mn    = fmaxf(m, s);
                float alpha = __expf(m - mn);     // m=-inf first edge -> 0
                float p     = __expf(s - mn);
                l = l * alpha + p;
                #pragma unroll
                for (int q = 0; q < 8; ++q)
                    acc[q] = acc[q] * alpha + p * b2f(vt[q]);
                m = mn;
            }
        }
        short8 o;
        #pragma unroll
        for (int q = 0; q < 8; ++q) o[q] = (short)f2b(acc[q]);
        *((short8*)(accb + (size_t)head * EMBED) + lane) = o;
        if (lane == 0) { mh[head] = m; lh[head] = l; }
    }
    __shared__ float smax[256];
    smax[tid] = m;
    __syncthreads();
    for (int off = 128; off > 0; off >>= 1) {
        if (tid < off) smax[tid] = fmaxf(smax[tid], smax[tid + off]);
        __syncthreads();
    }
    if (tid == 0) blockmax[blockIdx.x] = smax[0];
}

// ---------------- K3b: reduce blockmax -> M ----------------
__global__ __launch_bounds__(256) void k_maxred(
    const float* __restrict__ blockmax, float* __restrict__ Mout, int n)
{
    __shared__ float smax[256];
    float m = -INFINITY;
    for (int i = threadIdx.x; i < n; i += 256) m = fmaxf(m, blockmax[i]);
    smax[threadIdx.x] = m;
    __syncthreads();
    for (int off = 128; off > 0; off >>= 1) {
        if ((int)threadIdx.x < off)
            smax[threadIdx.x] = fmaxf(smax[threadIdx.x], smax[threadIdx.x + off]);
        __syncthreads();
    }
    if (threadIdx.x == 0) Mout[0] = smax[0];
}

// ---------------- K4: fused normalize + x = ent + agg + bf16 MFMA GEMM ----------------
// x[g] = entb[g] + accb[g] / (lh[g] + 1e-10*exp(M - mh[g])); out = leaky_relu(x @ W^T).
__global__ __launch_bounds__(256) void k_gemm_f(
    const short* __restrict__ entb, const short* __restrict__ accb,
    const float* __restrict__ mh, const float* __restrict__ lh,
    const float* __restrict__ Mptr, const short* __restrict__ wb,
    float* __restrict__ out, int N)
{
    __shared__ short xs[128 * LDSPAD];
    __shared__ short ws[128 * LDSPAD];
    const int tid = threadIdx.x;
    const int n0  = blockIdx.x * 128;
    const float M = Mptr[0];

    // stage W (pre-cast bf16): 2048 short8 chunks, 8 per thread
    #pragma unroll
    for (int it = 0; it < 8; ++it) {
        int ch = it * 256 + tid;
        int row = ch >> 4, col8 = ch & 15;
        *(short8*)(ws + row * LDSPAD + col8 * 8) = ((const short8*)wb)[ch];
    }
    // stage x = ent + acc*inv: 2048 short8 chunks, 8 per thread
    #pragma unroll
    for (int it = 0; it < 8; ++it) {
        int ch = it * 256 + tid;
        int row = ch >> 4, col8 = ch & 15;
        int g = n0 + row;
        short8 v = {0,0,0,0,0,0,0,0};
        if (g < N) {
            float inv = 1.0f / (lh[g] + 1e-10f * __expf(M - mh[g]));  // inf -> 0 (degenerate head)
            short8 e8 = *((const short8*)(entb + (size_t)g * EMBED) + col8);
            short8 a8 = *((const short8*)(accb + (size_t)g * EMBED) + col8);
            #pragma unroll
            for (int q = 0; q < 8; ++q)
                v[q] = (short)f2b(b2f(e8[q]) + b2f(a8[q]) * inv);
        }
        *(short8*)(xs + row * LDSPAD + col8 * 8) = v;
    }
    __syncthreads();

    const int wv   = tid >> 6;
    const int lane = tid & 63;
    const int n16  = lane & 15;
    const int quad = lane >> 4;

    floatx4 acc[2][8];
    #pragma unroll
    for (int rt = 0; rt < 2; ++rt)
        #pragma unroll
        for (int jt = 0; jt < 8; ++jt)
            acc[rt][jt] = (floatx4){0.f, 0.f, 0.f, 0.f};

    #pragma unroll
    for (int kc = 0; kc < 4; ++kc) {
        int koff = kc * 32 + quad * 8;
        short8 a0 = *(const short8*)(xs + (wv * 32      + n16) * LDSPAD + koff);
        short8 a1 = *(const short8*)(xs + (wv * 32 + 16 + n16) * LDSPAD + koff);
        #pragma unroll
        for (int jt = 0; jt < 8; ++jt) {
            short8 b = *(const short8*)(ws + (jt * 16 + n16) * LDSPAD + koff);
            acc[0][jt] = __builtin_amdgcn_mfma_f32_16x16x32_bf16(a0, b, acc[0][jt], 0, 0, 0);
            acc[1][jt] = __builtin_amdgcn_mfma_f32_16x16x32_bf16(a1, b, acc[1][jt], 0, 0, 0);
        }
    }

    #pragma unroll
    for (int rt = 0; rt < 2; ++rt) {
        int rowbase = n0 + wv * 32 + rt * 16 + quad * 4;
        #pragma unroll
        for (int r = 0; r < 4; ++r) {
            int grow = rowbase + r;
            if (grow < N) {
                float* o = out + (size_t)grow * EMBED + n16;
                #pragma unroll
                for (int jt = 0; jt < 8; ++jt) {
                    float v = acc[rt][jt][r];
                    o[jt * 16] = (v > 0.f) ? v : 0.2f * v;
                }
            }
        }
    }
}

extern "C" void kernel_launch(void* const* d_in, const int* in_sizes, int n_in,
                              void* d_out, int out_size, void* d_ws, size_t ws_size,
                              hipStream_t stream)
{
    const float* ent   = (const float*)d_in[0];   // entity_emb  [N,128] fp32
    const float* rel   = (const float*)d_in[1];   // rel_embed   [R,128] fp32
    const float* W     = (const float*)d_in[2];   // W           [128,128] fp32
    const int*   heads = (const int*)d_in[3];
    const int*   rels  = (const int*)d_in[4];
    const int*   tails = (const int*)d_in[5];
    const int E = in_sizes[3];
    const int N = in_sizes[0] / EMBED;
    const int R = in_sizes[1] / EMBED;
    float* out = (float*)d_out;

    // ws layout:
    // accb[N*128]s | mh[N]f | lh[N]f | tr[E]int2 | cnt[N]i | offs[N]i | cursor[N]i |
    // blockmax[BMAX]f | Mval[4]f | bsum[1024]i | ghist[64]i | dbase[64]i | order[N]i |
    // wb[16384]s | entb[N*128]s | relb[R*128]s
    short* accb     = (short*)d_ws;
    float* mh       = (float*)(accb + (size_t)N * EMBED);
    float* lh       = mh + N;
    int2*  tr       = (int2*)(lh + N);
    int*   cnt      = (int*)(tr + E);
    int*   offs     = cnt + N;
    int*   cursor   = offs + N;
    float* blockmax = (float*)(cursor + N);
    float* Mval     = blockmax + BMAX;
    int*   bsum     = (int*)(Mval + 4);             // 16 B slot keeps alignment
    int*   ghist    = bsum + 1024;
    int*   dbase    = ghist + DBINS;
    int*   order    = dbase + DBINS;
    short* wb       = (short*)(order + N);          // 128*128 bf16 = 32 KB
    short* entb     = wb + 16384;
    short* relb     = entb + (size_t)N * EMBED;

    const int nb  = (N + 1023) >> 10;       // scan blocks
    const int ngh = (N + 15) / 16;          // per-head group blocks

    hipMemsetAsync(cnt, 0, (size_t)N * sizeof(int), stream);

    int ngE = N * EMBED / 8, ngR = R * EMBED / 8, ngW = EMBED * EMBED / 8;
    k_cast_hist<<<2048, 256, 0, stream>>>(ent, rel, W, entb, relb, wb, heads, cnt, ghist, ngE, ngR, ngW, E);
    k_scan1<<<nb, 1024, 0, stream>>>(cnt, offs, bsum, ghist, N);
    k_scan2<<<1, 1024, 0, stream>>>(bsum, ghist, dbase, nb);
    k_scan3<<<(N + 255) / 256, 256, 0, stream>>>(offs, bsum, cursor, cnt, dbase, order, N);
    k_csr<<<(E + 255) / 256, 256, 0, stream>>>(heads, rels, tails, cursor, tr, E);
    k_fused<<<ngh, 256, 0, stream>>>(entb, relb, offs, cnt, tr, order, accb, mh, lh, blockmax, N, R);
    k_maxred<<<1, 256, 0, stream>>>(blockmax, Mval, ngh);
    k_gemm_f<<<(N + 127) / 128, 256, 0, stream>>>(entb, accb, mh, lh, Mval, wb, out, N);
}

// Round 5
// 242.469 us; speedup vs baseline: 1.1642x; 1.0342x over previous
//
#include <hip/hip_runtime.h>
#include <math.h>

#define EMBED 128
#define BMAX 8192    // blockmax array (fused grid = ceil(N/16) = 6250 <= BMAX)
#define LDSPAD 136   // 128 + 8 bf16 pad -> 272 B row stride
#define DBINS 64     // degree bins for counting sort (deg clamped to 63)

#define TWO_LOG2E 2.8853900817779268f
#define DEFER_THR 32.0f

typedef __attribute__((ext_vector_type(8))) short short8;
typedef __attribute__((ext_vector_type(4))) float floatx4;

__device__ __forceinline__ float ex2(float x) { return __builtin_amdgcn_exp2f(x); }

__device__ __forceinline__ float fast_tanh2(float x) {     // 1 mul + 1 exp + 1 rcp
    float e = ex2(TWO_LOG2E * x);                           // x<<0 -> 0 -> -1; x>>0 -> inf -> 1
    return 1.0f - 2.0f * __builtin_amdgcn_rcpf(1.0f + e);
}

__device__ __forceinline__ unsigned short f2b(float f) {   // fp32 -> bf16 RNE
    union { float f; unsigned int u; } v; v.f = f;
    unsigned int r = v.u + 0x7FFFu + ((v.u >> 16) & 1u);
    return (unsigned short)(r >> 16);
}

__device__ __forceinline__ float b2f(short u) {
    union { float f; unsigned int i; } v;
    v.i = ((unsigned int)(unsigned short)u) << 16;
    return v.f;
}

// sum over the 16-lane DPP row via sum-of-rotations (exact allreduce):
// after adding ror1, ror2, ror4, ror8 each lane holds the row total.
// VALU-speed (no DS pipe) vs ds_bpermute-based __shfl_xor.
template <int CTRL>
__device__ __forceinline__ float dpp_add_f(float x) {
    int y = __builtin_amdgcn_update_dpp(0, __float_as_int(x), CTRL, 0xF, 0xF, false);
    return x + __int_as_float(y);
}
__device__ __forceinline__ float dpp_sum16(float s) {
    s = dpp_add_f<0x121>(s);   // row_ror:1
    s = dpp_add_f<0x122>(s);   // row_ror:2
    s = dpp_add_f<0x124>(s);   // row_ror:4
    s = dpp_add_f<0x128>(s);   // row_ror:8
    return s;
}

// ---------------- K0: cast ent/rel/W to bf16 + head histogram (+ zero ghist) ----------------
__global__ __launch_bounds__(256) void k_cast_hist(
    const float* __restrict__ ent, const float* __restrict__ rel, const float* __restrict__ W,
    short* __restrict__ entb, short* __restrict__ relb, short* __restrict__ wb,
    const int* __restrict__ heads, int* __restrict__ cnt, int* __restrict__ ghist,
    int ngE, int ngR, int ngW, int E)
{
    if (blockIdx.x == 0 && threadIdx.x < DBINS) ghist[threadIdx.x] = 0;  // no reader until k_scan1
    int stride = gridDim.x * 256;
    int total = ngE + ngR + ngW;
    for (int g = blockIdx.x * 256 + threadIdx.x; g < total; g += stride) {
        const float4* src; short* dst;
        if (g < ngE)            { src = (const float4*)ent + (size_t)g * 2;              dst = entb + (size_t)g * 8; }
        else if (g < ngE + ngR) { int g2 = g - ngE;       src = (const float4*)rel + (size_t)g2 * 2; dst = relb + (size_t)g2 * 8; }
        else                    { int g2 = g - ngE - ngR; src = (const float4*)W   + (size_t)g2 * 2; dst = wb   + (size_t)g2 * 8; }
        float4 a = src[0], b = src[1];
        short8 o;
        o[0] = (short)f2b(a.x); o[1] = (short)f2b(a.y); o[2] = (short)f2b(a.z); o[3] = (short)f2b(a.w);
        o[4] = (short)f2b(b.x); o[5] = (short)f2b(b.y); o[6] = (short)f2b(b.z); o[7] = (short)f2b(b.w);
        *(short8*)dst = o;
    }
    for (int e = blockIdx.x * 256 + threadIdx.x; e < E; e += stride)
        atomicAdd(cnt + heads[e], 1);
}

// ---------------- K1a: block scan of cnt + degree histogram ----------------
__global__ __launch_bounds__(1024) void k_scan1(
    const int* __restrict__ cnt, int* __restrict__ offs,
    int* __restrict__ bsum, int* __restrict__ ghist, int N)
{
    __shared__ int wsum[16];
    __shared__ int dh[DBINS];
    const int tid = threadIdx.x;
    if (tid < DBINS) dh[tid] = 0;
    int i = blockIdx.x * 1024 + tid;
    int v = (i < N) ? cnt[i] : 0;
    __syncthreads();
    if (i < N) atomicAdd(&dh[v < DBINS ? v : DBINS - 1], 1);
    int x = v;
    #pragma unroll
    for (int d = 1; d < 64; d <<= 1) {
        int y = __shfl_up(x, d, 64);
        if ((tid & 63) >= d) x += y;
    }
    if ((tid & 63) == 63) wsum[tid >> 6] = x;
    __syncthreads();
    if (tid < 16) {
        int w = wsum[tid];
        #pragma unroll
        for (int d = 1; d < 16; d <<= 1) {
            int y = __shfl_up(w, d, 16);
            if (tid >= d) w += y;
        }
        wsum[tid] = w;
    }
    __syncthreads();
    int add = (tid >= 64) ? wsum[(tid >> 6) - 1] : 0;
    int incl = x + add;
    if (i < N) offs[i] = incl - v;
    if (tid == 1023) bsum[blockIdx.x] = incl;
    if (tid < DBINS && dh[tid] > 0) atomicAdd(ghist + tid, dh[tid]);
}

// ---------------- K1b: finalize offs/cursor + counting-sort scatter (scan2 folded in) ----------------
// Each block redundantly scans bsum (nb <= 256) and ghist (64 bins) with shuffles;
// per-bin global ranges reserved via bincur (zeroed by the launch memset).
__global__ __launch_bounds__(256) void k_scan23(
    int* __restrict__ offs, const int* __restrict__ bsum,
    int* __restrict__ cursor, const int* __restrict__ cnt,
    const int* __restrict__ ghist, int* __restrict__ bincur,
    int* __restrict__ order, int N, int nb)
{
    __shared__ int sb[256];      // exclusive-scanned bsum
    __shared__ int ws4[4];
    __shared__ int dbs[DBINS];   // exclusive-scanned ghist
    __shared__ int lcnt[DBINS];
    __shared__ int lbase[DBINS];
    const int tid = threadIdx.x;

    int v = (tid < nb) ? bsum[tid] : 0;
    int x = v;
    #pragma unroll
    for (int d = 1; d < 64; d <<= 1) {
        int y = __shfl_up(x, d, 64);
        if ((tid & 63) >= d) x += y;
    }
    if ((tid & 63) == 63) ws4[tid >> 6] = x;
    __syncthreads();
    if (tid < 4) {
        int w = ws4[tid];
        #pragma unroll
        for (int d = 1; d < 4; d <<= 1) {
            int y = __shfl_up(w, d, 4);
            if (tid >= d) w += y;
        }
        ws4[tid] = w;
    }
    __syncthreads();
    int add = (tid >= 64) ? ws4[(tid >> 6) - 1] : 0;
    sb[tid] = x + add - v;            // exclusive prefix of bsum

    if (tid < 64) {                   // ghist exclusive scan (one wave)
        int g = ghist[tid];
        int s = g;
        #pragma unroll
        for (int d = 1; d < 64; d <<= 1) {
            int y = __shfl_up(s, d, 64);
            if (tid >= d) s += y;
        }
        dbs[tid] = s - g;
    }
    if (tid < DBINS) lcnt[tid] = 0;
    __syncthreads();

    int i = blockIdx.x * 256 + tid;
    int deg = 0, lrank = 0;
    if (i < N) {
        int o = offs[i] + sb[i >> 10];
        offs[i] = o;
        cursor[i] = o;
        int c = cnt[i];
        deg = c < DBINS ? c : DBINS - 1;
        lrank = atomicAdd(&lcnt[deg], 1);          // local rank within block
    }
    __syncthreads();
    if (tid < DBINS) {
        int n = lcnt[tid];
        lbase[tid] = (n > 0) ? (dbs[tid] + atomicAdd(bincur + tid, n)) : 0;
    }
    __syncthreads();
    if (i < N) order[lbase[deg] + lrank] = i;
}

// ---------------- K2: CSR slot-fill: packed (tail, rel) per slot ----------------
__global__ __launch_bounds__(256) void k_csr(
    const int* __restrict__ heads, const int* __restrict__ rels,
    const int* __restrict__ tails, int* __restrict__ cursor,
    int2* __restrict__ tr, int E)
{
    int e = blockIdx.x * 256 + threadIdx.x;
    if (e >= E) return;
    int pos = atomicAdd(cursor + heads[e], 1);
    tr[pos] = make_int2(tails[e], rels[e]);
}

// ---------------- K3: fused score + online-softmax aggregate ----------------
// 16 lanes per head; degree-sorted order. j-body changes vs r4 (loads untouched):
//  - DPP row_ror sum (VALU) replaces 4 ds_bpermute __shfl_xor
//  - deferred rescale: common path = 1 exp + 9 fma; (m,l,acc) stay shift-consistent
//  - mt tracks the TRUE max for blockmax/M (epsilon semantics exact)
//  - vtf[8] caches b2f(vt) for reuse in the accumulate
__global__ __launch_bounds__(256) void k_fused(
    const short* __restrict__ entb, const short* __restrict__ relb,
    const int* __restrict__ offs, const int* __restrict__ cnt,
    const int2* __restrict__ tr, const int* __restrict__ order,
    short* __restrict__ accb, float* __restrict__ mh, float* __restrict__ lh,
    float* __restrict__ blockmax, int N, int R)
{
    __shared__ short rl[64 * EMBED];   // 16 KB rel table cache
    const int tid = threadIdx.x;
    if (R <= 64) {
        int nch = R * 16;
        for (int i = tid; i < nch; i += 256)
            ((short8*)rl)[i] = ((const short8*)relb)[i];
    }
    __syncthreads();
    const short* relsrc = (R <= 64) ? (const short*)rl : relb;

    const int lane = tid & 15;
    int head0 = blockIdx.x * 16 + (tid >> 4);
    int head  = (head0 < N) ? order[head0] : N;
    float mt = -INFINITY;              // true max (for global M)
    if (head < N) {
        int start = offs[head];
        int c     = cnt[head];
        short8 hh = *((const short8*)(entb + (size_t)head * EMBED) + lane);
        float hf[8];
        #pragma unroll
        for (int i = 0; i < 8; ++i) hf[i] = b2f(hh[i]);
        float m = -INFINITY;           // deferred reference point
        float l = 0.f;
        float acc[8] = {0,0,0,0,0,0,0,0};
        for (int base = 0; base < c; base += 16) {
            int rem = c - base;
            int mm  = rem < 16 ? rem : 16;
            int2 trv = make_int2(0, 0);
            if (lane < mm) trv = tr[start + base + lane];
            for (int j = 0; j < mm; ++j) {
                int t = __shfl(trv.x, j, 16);
                int r = __shfl(trv.y, j, 16);
                short8 vt = *((const short8*)(entb + (size_t)t * EMBED) + lane);
                short8 vr = *((const short8*)(relsrc + (size_t)r * EMBED) + lane);
                float s = 0.f;
                float vtf[8];
                #pragma unroll
                for (int i = 0; i < 8; ++i) {
                    vtf[i] = b2f(vt[i]);
                    s = fmaf(vtf[i], fast_tanh2(hf[i] + b2f(vr[i])), s);
                }
                s = dpp_sum16(s);
                mt = fmaxf(mt, s);
                float dlt = s - m;                 // first edge: +inf
                if (dlt > DEFER_THR) {             // rare after j=0 (j=0 is synchronized)
                    float alpha = __expf(-dlt);    // exp(m - s); -inf -> 0
                    l *= alpha;
                    #pragma unroll
                    for (int q = 0; q < 8; ++q) acc[q] *= alpha;
                    m = s;
                    dlt = 0.f;
                }
                float p = __expf(dlt);             // p <= e^32: fp32-safe
                l += p;
                #pragma unroll
                for (int q = 0; q < 8; ++q)
                    acc[q] = fmaf(p, vtf[q], acc[q]);
            }
        }
        short8 o;
        #pragma unroll
        for (int q = 0; q < 8; ++q) o[q] = (short)f2b(acc[q]);
        *((short8*)(accb + (size_t)head * EMBED) + lane) = o;
        if (lane == 0) { mh[head] = m; lh[head] = l; }
    }
    __shared__ float smax[256];
    smax[tid] = mt;
    __syncthreads();
    for (int off = 128; off > 0; off >>= 1) {
        if (tid < off) smax[tid] = fmaxf(smax[tid], smax[tid + off]);
        __syncthreads();
    }
    if (tid == 0) blockmax[blockIdx.x] = smax[0];
}

// ---------------- K3b: reduce blockmax -> M ----------------
__global__ __launch_bounds__(256) void k_maxred(
    const float* __restrict__ blockmax, float* __restrict__ Mout, int n)
{
    __shared__ float smax[256];
    float m = -INFINITY;
    for (int i = threadIdx.x; i < n; i += 256) m = fmaxf(m, blockmax[i]);
    smax[threadIdx.x] = m;
    __syncthreads();
    for (int off = 128; off > 0; off >>= 1) {
        if ((int)threadIdx.x < off)
            smax[threadIdx.x] = fmaxf(smax[threadIdx.x], smax[threadIdx.x + off]);
        __syncthreads();
    }
    if (threadIdx.x == 0) Mout[0] = smax[0];
}

// ---------------- K4: fused normalize + x = ent + agg + bf16 MFMA GEMM ----------------
// x[g] = entb[g] + accb[g] * inv[g]; inv = 1/(lh + 1e-10*exp(M - mh)); out = leaky_relu(x @ W^T).
__global__ __launch_bounds__(256) void k_gemm_f(
    const short* __restrict__ entb, const short* __restrict__ accb,
    const float* __restrict__ mh, const float* __restrict__ lh,
    const float* __restrict__ Mptr, const short* __restrict__ wb,
    float* __restrict__ out, int N)
{
    __shared__ short xs[128 * LDSPAD];
    __shared__ short ws[128 * LDSPAD];
    __shared__ float invs[128];
    const int tid = threadIdx.x;
    const int n0  = blockIdx.x * 128;
    const float M = Mptr[0];

    if (tid < 128) {
        int g = n0 + tid;
        invs[tid] = (g < N) ? 1.0f / (lh[g] + 1e-10f * __expf(M - mh[g])) : 0.f;  // inf -> 0
    }
    // stage W (pre-cast bf16): 2048 short8 chunks, 8 per thread
    #pragma unroll
    for (int it = 0; it < 8; ++it) {
        int ch = it * 256 + tid;
        int row = ch >> 4, col8 = ch & 15;
        *(short8*)(ws + row * LDSPAD + col8 * 8) = ((const short8*)wb)[ch];
    }
    __syncthreads();
    // stage x = ent + acc*inv: 2048 short8 chunks, 8 per thread
    #pragma unroll
    for (int it = 0; it < 8; ++it) {
        int ch = it * 256 + tid;
        int row = ch >> 4, col8 = ch & 15;
        int g = n0 + row;
        short8 v = {0,0,0,0,0,0,0,0};
        if (g < N) {
            float inv = invs[row];
            short8 e8 = *((const short8*)(entb + (size_t)g * EMBED) + col8);
            short8 a8 = *((const short8*)(accb + (size_t)g * EMBED) + col8);
            #pragma unroll
            for (int q = 0; q < 8; ++q)
                v[q] = (short)f2b(b2f(e8[q]) + b2f(a8[q]) * inv);
        }
        *(short8*)(xs + row * LDSPAD + col8 * 8) = v;
    }
    __syncthreads();

    const int wv   = tid >> 6;
    const int lane = tid & 63;
    const int n16  = lane & 15;
    const int quad = lane >> 4;

    floatx4 acc[2][8];
    #pragma unroll
    for (int rt = 0; rt < 2; ++rt)
        #pragma unroll
        for (int jt = 0; jt < 8; ++jt)
            acc[rt][jt] = (floatx4){0.f, 0.f, 0.f, 0.f};

    #pragma unroll
    for (int kc = 0; kc < 4; ++kc) {
        int koff = kc * 32 + quad * 8;
        short8 a0 = *(const short8*)(xs + (wv * 32      + n16) * LDSPAD + koff);
        short8 a1 = *(const short8*)(xs + (wv * 32 + 16 + n16) * LDSPAD + koff);
        #pragma unroll
        for (int jt = 0; jt < 8; ++jt) {
            short8 b = *(const short8*)(ws + (jt * 16 + n16) * LDSPAD + koff);
            acc[0][jt] = __builtin_amdgcn_mfma_f32_16x16x32_bf16(a0, b, acc[0][jt], 0, 0, 0);
            acc[1][jt] = __builtin_amdgcn_mfma_f32_16x16x32_bf16(a1, b, acc[1][jt], 0, 0, 0);
        }
    }

    #pragma unroll
    for (int rt = 0; rt < 2; ++rt) {
        int rowbase = n0 + wv * 32 + rt * 16 + quad * 4;
        #pragma unroll
        for (int r = 0; r < 4; ++r) {
            int grow = rowbase + r;
            if (grow < N) {
                float* o = out + (size_t)grow * EMBED + n16;
                #pragma unroll
                for (int jt = 0; jt < 8; ++jt) {
                    float v = acc[rt][jt][r];
                    o[jt * 16] = (v > 0.f) ? v : 0.2f * v;
                }
            }
        }
    }
}

extern "C" void kernel_launch(void* const* d_in, const int* in_sizes, int n_in,
                              void* d_out, int out_size, void* d_ws, size_t ws_size,
                              hipStream_t stream)
{
    const float* ent   = (const float*)d_in[0];   // entity_emb  [N,128] fp32
    const float* rel   = (const float*)d_in[1];   // rel_embed   [R,128] fp32
    const float* W     = (const float*)d_in[2];   // W           [128,128] fp32
    const int*   heads = (const int*)d_in[3];
    const int*   rels  = (const int*)d_in[4];
    const int*   tails = (const int*)d_in[5];
    const int E = in_sizes[3];
    const int N = in_sizes[0] / EMBED;
    const int R = in_sizes[1] / EMBED;
    float* out = (float*)d_out;

    // ws layout:
    // accb[N*128]s | mh[N]f | lh[N]f | tr[E]int2 | cnt[N]i | bincur[64]i | offs[N]i |
    // cursor[N]i | blockmax[BMAX]f | Mval[4]f | bsum[1024]i | ghist[64]i | order[N]i |
    // wb[16384]s | entb[N*128]s | relb[R*128]s
    short* accb     = (short*)d_ws;
    float* mh       = (float*)(accb + (size_t)N * EMBED);
    float* lh       = mh + N;
    int2*  tr       = (int2*)(lh + N);
    int*   cnt      = (int*)(tr + E);
    int*   bincur   = cnt + N;                      // zeroed together with cnt
    int*   offs     = bincur + DBINS;
    int*   cursor   = offs + N;
    float* blockmax = (float*)(cursor + N);
    float* Mval     = blockmax + BMAX;
    int*   bsum     = (int*)(Mval + 4);             // 16 B slot keeps alignment
    int*   ghist    = bsum + 1024;
    int*   order    = ghist + DBINS;
    short* wb       = (short*)(order + N);          // 128*128 bf16 = 32 KB
    short* entb     = wb + 16384;
    short* relb     = entb + (size_t)N * EMBED;

    const int nb  = (N + 1023) >> 10;       // scan blocks (<= 256 assumed: N <= 262144)
    const int ngh = (N + 15) / 16;          // per-head group blocks

    hipMemsetAsync(cnt, 0, (size_t)(N + DBINS) * sizeof(int), stream);

    int ngE = N * EMBED / 8, ngR = R * EMBED / 8, ngW = EMBED * EMBED / 8;
    k_cast_hist<<<2048, 256, 0, stream>>>(ent, rel, W, entb, relb, wb, heads, cnt, ghist, ngE, ngR, ngW, E);
    k_scan1<<<nb, 1024, 0, stream>>>(cnt, offs, bsum, ghist, N);
    k_scan23<<<(N + 255) / 256, 256, 0, stream>>>(offs, bsum, cursor, cnt, ghist, bincur, order, N, nb);
    k_csr<<<(E + 255) / 256, 256, 0, stream>>>(heads, rels, tails, cursor, tr, E);
    k_fused<<<ngh, 256, 0, stream>>>(entb, relb, offs, cnt, tr, order, accb, mh, lh, blockmax, N, R);
    k_maxred<<<1, 256, 0, stream>>>(blockmax, Mval, ngh);
    k_gemm_f<<<(N + 127) / 128, 256, 0, stream>>>(entb, accb, mh, lh, Mval, wb, out, N);
}

// Round 6
// 238.501 us; speedup vs baseline: 1.1836x; 1.0166x over previous
//
#include <hip/hip_runtime.h>
#include <math.h>

#define EMBED 128
#define BMAX 8192    // blockmax array (fused grid = ceil(N/16) = 6250 <= BMAX)
#define LDSPAD 136   // 128 + 8 bf16 pad -> 272 B row stride
#define DBINS 64     // degree bins for counting sort (deg clamped to 63)

#define TWO_LOG2E 2.8853900817779268f
#define DEFER_THR 32.0f

typedef __attribute__((ext_vector_type(8))) short short8;
typedef __attribute__((ext_vector_type(4))) float floatx4;

__device__ __forceinline__ float ex2(float x) { return __builtin_amdgcn_exp2f(x); }

__device__ __forceinline__ float fast_tanh2(float x) {     // 1 mul + 1 exp + 1 rcp
    float e = ex2(TWO_LOG2E * x);                           // x<<0 -> 0 -> -1; x>>0 -> inf -> 1
    return 1.0f - 2.0f * __builtin_amdgcn_rcpf(1.0f + e);
}

__device__ __forceinline__ unsigned short f2b(float f) {   // fp32 -> bf16 RNE
    union { float f; unsigned int u; } v; v.f = f;
    unsigned int r = v.u + 0x7FFFu + ((v.u >> 16) & 1u);
    return (unsigned short)(r >> 16);
}

__device__ __forceinline__ float b2f(short u) {
    union { float f; unsigned int i; } v;
    v.i = ((unsigned int)(unsigned short)u) << 16;
    return v.f;
}

// sum over the 16-lane DPP row via sum-of-rotations (exact allreduce)
template <int CTRL>
__device__ __forceinline__ float dpp_add_f(float x) {
    int y = __builtin_amdgcn_update_dpp(0, __float_as_int(x), CTRL, 0xF, 0xF, false);
    return x + __int_as_float(y);
}
__device__ __forceinline__ float dpp_sum16(float s) {
    s = dpp_add_f<0x121>(s);   // row_ror:1
    s = dpp_add_f<0x122>(s);   // row_ror:2
    s = dpp_add_f<0x124>(s);   // row_ror:4
    s = dpp_add_f<0x128>(s);   // row_ror:8
    return s;
}

// ---------------- K0: cast ent/rel/W to bf16 + head histogram (+ zero ghist) ----------------
__global__ __launch_bounds__(256) void k_cast_hist(
    const float* __restrict__ ent, const float* __restrict__ rel, const float* __restrict__ W,
    short* __restrict__ entb, short* __restrict__ relb, short* __restrict__ wb,
    const int* __restrict__ heads, int* __restrict__ cnt, int* __restrict__ ghist,
    int ngE, int ngR, int ngW, int E)
{
    if (blockIdx.x == 0 && threadIdx.x < DBINS) ghist[threadIdx.x] = 0;  // no reader until k_scan1
    int stride = gridDim.x * 256;
    int total = ngE + ngR + ngW;
    for (int g = blockIdx.x * 256 + threadIdx.x; g < total; g += stride) {
        const float4* src; short* dst;
        if (g < ngE)            { src = (const float4*)ent + (size_t)g * 2;              dst = entb + (size_t)g * 8; }
        else if (g < ngE + ngR) { int g2 = g - ngE;       src = (const float4*)rel + (size_t)g2 * 2; dst = relb + (size_t)g2 * 8; }
        else                    { int g2 = g - ngE - ngR; src = (const float4*)W   + (size_t)g2 * 2; dst = wb   + (size_t)g2 * 8; }
        float4 a = src[0], b = src[1];
        short8 o;
        o[0] = (short)f2b(a.x); o[1] = (short)f2b(a.y); o[2] = (short)f2b(a.z); o[3] = (short)f2b(a.w);
        o[4] = (short)f2b(b.x); o[5] = (short)f2b(b.y); o[6] = (short)f2b(b.z); o[7] = (short)f2b(b.w);
        *(short8*)dst = o;
    }
    for (int e = blockIdx.x * 256 + threadIdx.x; e < E; e += stride)
        atomicAdd(cnt + heads[e], 1);
}

// ---------------- K1a: block scan of cnt + degree histogram ----------------
__global__ __launch_bounds__(1024) void k_scan1(
    const int* __restrict__ cnt, int* __restrict__ offs,
    int* __restrict__ bsum, int* __restrict__ ghist, int N)
{
    __shared__ int wsum[16];
    __shared__ int dh[DBINS];
    const int tid = threadIdx.x;
    if (tid < DBINS) dh[tid] = 0;
    int i = blockIdx.x * 1024 + tid;
    int v = (i < N) ? cnt[i] : 0;
    __syncthreads();
    if (i < N) atomicAdd(&dh[v < DBINS ? v : DBINS - 1], 1);
    int x = v;
    #pragma unroll
    for (int d = 1; d < 64; d <<= 1) {
        int y = __shfl_up(x, d, 64);
        if ((tid & 63) >= d) x += y;
    }
    if ((tid & 63) == 63) wsum[tid >> 6] = x;
    __syncthreads();
    if (tid < 16) {
        int w = wsum[tid];
        #pragma unroll
        for (int d = 1; d < 16; d <<= 1) {
            int y = __shfl_up(w, d, 16);
            if (tid >= d) w += y;
        }
        wsum[tid] = w;
    }
    __syncthreads();
    int add = (tid >= 64) ? wsum[(tid >> 6) - 1] : 0;
    int incl = x + add;
    if (i < N) offs[i] = incl - v;
    if (tid == 1023) bsum[blockIdx.x] = incl;
    if (tid < DBINS && dh[tid] > 0) atomicAdd(ghist + tid, dh[tid]);
}

// ---------------- K1b: finalize offs/cursor + counting-sort scatter (scan2 folded in) ----------------
__global__ __launch_bounds__(256) void k_scan23(
    int* __restrict__ offs, const int* __restrict__ bsum,
    int* __restrict__ cursor, const int* __restrict__ cnt,
    const int* __restrict__ ghist, int* __restrict__ bincur,
    int* __restrict__ order, int N, int nb)
{
    __shared__ int sb[256];      // exclusive-scanned bsum
    __shared__ int ws4[4];
    __shared__ int dbs[DBINS];   // exclusive-scanned ghist
    __shared__ int lcnt[DBINS];
    __shared__ int lbase[DBINS];
    const int tid = threadIdx.x;

    int v = (tid < nb) ? bsum[tid] : 0;
    int x = v;
    #pragma unroll
    for (int d = 1; d < 64; d <<= 1) {
        int y = __shfl_up(x, d, 64);
        if ((tid & 63) >= d) x += y;
    }
    if ((tid & 63) == 63) ws4[tid >> 6] = x;
    __syncthreads();
    if (tid < 4) {
        int w = ws4[tid];
        #pragma unroll
        for (int d = 1; d < 4; d <<= 1) {
            int y = __shfl_up(w, d, 4);
            if (tid >= d) w += y;
        }
        ws4[tid] = w;
    }
    __syncthreads();
    int add = (tid >= 64) ? ws4[(tid >> 6) - 1] : 0;
    sb[tid] = x + add - v;            // exclusive prefix of bsum

    if (tid < 64) {                   // ghist exclusive scan (one wave)
        int g = ghist[tid];
        int s = g;
        #pragma unroll
        for (int d = 1; d < 64; d <<= 1) {
            int y = __shfl_up(s, d, 64);
            if (tid >= d) s += y;
        }
        dbs[tid] = s - g;
    }
    if (tid < DBINS) lcnt[tid] = 0;
    __syncthreads();

    int i = blockIdx.x * 256 + tid;
    int deg = 0, lrank = 0;
    if (i < N) {
        int o = offs[i] + sb[i >> 10];
        offs[i] = o;
        cursor[i] = o;
        int c = cnt[i];
        deg = c < DBINS ? c : DBINS - 1;
        lrank = atomicAdd(&lcnt[deg], 1);          // local rank within block
    }
    __syncthreads();
    if (tid < DBINS) {
        int n = lcnt[tid];
        lbase[tid] = (n > 0) ? (dbs[tid] + atomicAdd(bincur + tid, n)) : 0;
    }
    __syncthreads();
    if (i < N) order[lbase[deg] + lrank] = i;
}

// ---------------- K2: CSR slot-fill: packed (tail, rel) per slot ----------------
__global__ __launch_bounds__(256) void k_csr(
    const int* __restrict__ heads, const int* __restrict__ rels,
    const int* __restrict__ tails, int* __restrict__ cursor,
    int2* __restrict__ tr, int E)
{
    int e = blockIdx.x * 256 + threadIdx.x;
    if (e >= E) return;
    int pos = atomicAdd(cursor + heads[e], 1);
    tr[pos] = make_int2(tails[e], rels[e]);
}

// ---------------- K3: fused score + online-softmax aggregate ----------------
// 16 lanes per head; DESCENDING degree order (LPT: heavy blocks first).
// No rel LDS staging (relb is 16 KB, L1-resident). Depth-1 branchless
// prefetch of vt/vr hides gather latency under the exp chain.
// j-body math identical to the verified r5 body.
__global__ __launch_bounds__(256) void k_fused(
    const short* __restrict__ entb, const short* __restrict__ relb,
    const int* __restrict__ offs, const int* __restrict__ cnt,
    const int2* __restrict__ tr, const int* __restrict__ order,
    short* __restrict__ accb, float* __restrict__ mh, float* __restrict__ lh,
    float* __restrict__ blockmax, int N, int R)
{
    const int tid = threadIdx.x;
    const int lane = tid & 15;
    int head0 = blockIdx.x * 16 + (tid >> 4);
    int head  = (head0 < N) ? order[(N - 1) - head0] : N;   // reverse = descending degree
    float mt = -INFINITY;              // true max (for global M)
    if (head < N) {
        int start = offs[head];
        int c     = cnt[head];
        short8 hh = *((const short8*)(entb + (size_t)head * EMBED) + lane);
        float hf[8];
        #pragma unroll
        for (int i = 0; i < 8; ++i) hf[i] = b2f(hh[i]);
        float m = -INFINITY;           // deferred reference point
        float l = 0.f;
        float acc[8] = {0,0,0,0,0,0,0,0};
        for (int base = 0; base < c; base += 16) {
            int rem = c - base;
            int mm  = rem < 16 ? rem : 16;
            int2 trv = make_int2(0, 0);
            if (lane < mm) trv = tr[start + base + lane];
            int t0 = __shfl(trv.x, 0, 16);
            int r0 = __shfl(trv.y, 0, 16);
            short8 vtc = *((const short8*)(entb + (size_t)t0 * EMBED) + lane);
            short8 vrc = *((const short8*)(relb + (size_t)r0 * EMBED) + lane);
            for (int j = 0; j < mm; ++j) {
                int jn = (j + 1 < mm) ? j + 1 : j;       // clamp: last iter reloads (L1-hot)
                int tn = __shfl(trv.x, jn, 16);
                int rn = __shfl(trv.y, jn, 16);
                short8 vtn = *((const short8*)(entb + (size_t)tn * EMBED) + lane);
                short8 vrn = *((const short8*)(relb + (size_t)rn * EMBED) + lane);
                float s = 0.f;
                float vtf[8];
                #pragma unroll
                for (int i = 0; i < 8; ++i) {
                    vtf[i] = b2f(vtc[i]);
                    s = fmaf(vtf[i], fast_tanh2(hf[i] + b2f(vrc[i])), s);
                }
                s = dpp_sum16(s);
                mt = fmaxf(mt, s);
                float dlt = s - m;                 // first edge: +inf
                if (dlt > DEFER_THR) {             // rare after j=0 (j=0 synchronized)
                    float alpha = __expf(-dlt);    // exp(m - s); -inf -> 0
                    l *= alpha;
                    #pragma unroll
                    for (int q = 0; q < 8; ++q) acc[q] *= alpha;
                    m = s;
                    dlt = 0.f;
                }
                float p = __expf(dlt);             // p <= e^32: fp32-safe
                l += p;
                #pragma unroll
                for (int q = 0; q < 8; ++q)
                    acc[q] = fmaf(p, vtf[q], acc[q]);
                vtc = vtn;
                vrc = vrn;
            }
        }
        short8 o;
        #pragma unroll
        for (int q = 0; q < 8; ++q) o[q] = (short)f2b(acc[q]);
        *((short8*)(accb + (size_t)head * EMBED) + lane) = o;
        if (lane == 0) { mh[head] = m; lh[head] = l; }
    }
    // block max: wave shfl_xor reduce + 4-slot LDS + one barrier
    __shared__ float wmax[4];
    float wm = mt;
    #pragma unroll
    for (int off = 1; off < 64; off <<= 1) wm = fmaxf(wm, __shfl_xor(wm, off, 64));
    if ((tid & 63) == 0) wmax[tid >> 6] = wm;
    __syncthreads();
    if (tid == 0)
        blockmax[blockIdx.x] = fmaxf(fmaxf(wmax[0], wmax[1]), fmaxf(wmax[2], wmax[3]));
}

// ---------------- K3b: reduce blockmax -> M ----------------
__global__ __launch_bounds__(256) void k_maxred(
    const float* __restrict__ blockmax, float* __restrict__ Mout, int n)
{
    __shared__ float smax[256];
    float m = -INFINITY;
    for (int i = threadIdx.x; i < n; i += 256) m = fmaxf(m, blockmax[i]);
    smax[threadIdx.x] = m;
    __syncthreads();
    for (int off = 128; off > 0; off >>= 1) {
        if ((int)threadIdx.x < off)
            smax[threadIdx.x] = fmaxf(smax[threadIdx.x], smax[threadIdx.x + off]);
        __syncthreads();
    }
    if (threadIdx.x == 0) Mout[0] = smax[0];
}

// ---------------- K4: fused normalize + x = ent + agg + bf16 MFMA GEMM ----------------
__global__ __launch_bounds__(256) void k_gemm_f(
    const short* __restrict__ entb, const short* __restrict__ accb,
    const float* __restrict__ mh, const float* __restrict__ lh,
    const float* __restrict__ Mptr, const short* __restrict__ wb,
    float* __restrict__ out, int N)
{
    __shared__ short xs[128 * LDSPAD];
    __shared__ short ws[128 * LDSPAD];
    __shared__ float invs[128];
    const int tid = threadIdx.x;
    const int n0  = blockIdx.x * 128;
    const float M = Mptr[0];

    if (tid < 128) {
        int g = n0 + tid;
        invs[tid] = (g < N) ? 1.0f / (lh[g] + 1e-10f * __expf(M - mh[g])) : 0.f;  // inf -> 0
    }
    // stage W (pre-cast bf16): 2048 short8 chunks, 8 per thread
    #pragma unroll
    for (int it = 0; it < 8; ++it) {
        int ch = it * 256 + tid;
        int row = ch >> 4, col8 = ch & 15;
        *(short8*)(ws + row * LDSPAD + col8 * 8) = ((const short8*)wb)[ch];
    }
    __syncthreads();
    // stage x = ent + acc*inv: 2048 short8 chunks, 8 per thread
    #pragma unroll
    for (int it = 0; it < 8; ++it) {
        int ch = it * 256 + tid;
        int row = ch >> 4, col8 = ch & 15;
        int g = n0 + row;
        short8 v = {0,0,0,0,0,0,0,0};
        if (g < N) {
            float inv = invs[row];
            short8 e8 = *((const short8*)(entb + (size_t)g * EMBED) + col8);
            short8 a8 = *((const short8*)(accb + (size_t)g * EMBED) + col8);
            #pragma unroll
            for (int q = 0; q < 8; ++q)
                v[q] = (short)f2b(b2f(e8[q]) + b2f(a8[q]) * inv);
        }
        *(short8*)(xs + row * LDSPAD + col8 * 8) = v;
    }
    __syncthreads();

    const int wv   = tid >> 6;
    const int lane = tid & 63;
    const int n16  = lane & 15;
    const int quad = lane >> 4;

    floatx4 acc[2][8];
    #pragma unroll
    for (int rt = 0; rt < 2; ++rt)
        #pragma unroll
        for (int jt = 0; jt < 8; ++jt)
            acc[rt][jt] = (floatx4){0.f, 0.f, 0.f, 0.f};

    #pragma unroll
    for (int kc = 0; kc < 4; ++kc) {
        int koff = kc * 32 + quad * 8;
        short8 a0 = *(const short8*)(xs + (wv * 32      + n16) * LDSPAD + koff);
        short8 a1 = *(const short8*)(xs + (wv * 32 + 16 + n16) * LDSPAD + koff);
        #pragma unroll
        for (int jt = 0; jt < 8; ++jt) {
            short8 b = *(const short8*)(ws + (jt * 16 + n16) * LDSPAD + koff);
            acc[0][jt] = __builtin_amdgcn_mfma_f32_16x16x32_bf16(a0, b, acc[0][jt], 0, 0, 0);
            acc[1][jt] = __builtin_amdgcn_mfma_f32_16x16x32_bf16(a1, b, acc[1][jt], 0, 0, 0);
        }
    }

    #pragma unroll
    for (int rt = 0; rt < 2; ++rt) {
        int rowbase = n0 + wv * 32 + rt * 16 + quad * 4;
        #pragma unroll
        for (int r = 0; r < 4; ++r) {
            int grow = rowbase + r;
            if (grow < N) {
                float* o = out + (size_t)grow * EMBED + n16;
                #pragma unroll
                for (int jt = 0; jt < 8; ++jt) {
                    float v = acc[rt][jt][r];
                    o[jt * 16] = (v > 0.f) ? v : 0.2f * v;
                }
            }
        }
    }
}

extern "C" void kernel_launch(void* const* d_in, const int* in_sizes, int n_in,
                              void* d_out, int out_size, void* d_ws, size_t ws_size,
                              hipStream_t stream)
{
    const float* ent   = (const float*)d_in[0];   // entity_emb  [N,128] fp32
    const float* rel   = (const float*)d_in[1];   // rel_embed   [R,128] fp32
    const float* W     = (const float*)d_in[2];   // W           [128,128] fp32
    const int*   heads = (const int*)d_in[3];
    const int*   rels  = (const int*)d_in[4];
    const int*   tails = (const int*)d_in[5];
    const int E = in_sizes[3];
    const int N = in_sizes[0] / EMBED;
    const int R = in_sizes[1] / EMBED;
    float* out = (float*)d_out;

    // ws layout:
    // accb[N*128]s | mh[N]f | lh[N]f | tr[E]int2 | cnt[N]i | bincur[64]i | offs[N]i |
    // cursor[N]i | blockmax[BMAX]f | Mval[4]f | bsum[1024]i | ghist[64]i | order[N]i |
    // wb[16384]s | entb[N*128]s | relb[R*128]s
    short* accb     = (short*)d_ws;
    float* mh       = (float*)(accb + (size_t)N * EMBED);
    float* lh       = mh + N;
    int2*  tr       = (int2*)(lh + N);
    int*   cnt      = (int*)(tr + E);
    int*   bincur   = cnt + N;                      // zeroed together with cnt
    int*   offs     = bincur + DBINS;
    int*   cursor   = offs + N;
    float* blockmax = (float*)(cursor + N);
    float* Mval     = blockmax + BMAX;
    int*   bsum     = (int*)(Mval + 4);             // 16 B slot keeps alignment
    int*   ghist    = bsum + 1024;
    int*   order    = ghist + DBINS;
    short* wb       = (short*)(order + N);          // 128*128 bf16 = 32 KB
    short* entb     = wb + 16384;
    short* relb     = entb + (size_t)N * EMBED;

    const int nb  = (N + 1023) >> 10;       // scan blocks (<= 256 assumed: N <= 262144)
    const int ngh = (N + 15) / 16;          // per-head group blocks

    hipMemsetAsync(cnt, 0, (size_t)(N + DBINS) * sizeof(int), stream);

    int ngE = N * EMBED / 8, ngR = R * EMBED / 8, ngW = EMBED * EMBED / 8;
    k_cast_hist<<<2048, 256, 0, stream>>>(ent, rel, W, entb, relb, wb, heads, cnt, ghist, ngE, ngR, ngW, E);
    k_scan1<<<nb, 1024, 0, stream>>>(cnt, offs, bsum, ghist, N);
    k_scan23<<<(N + 255) / 256, 256, 0, stream>>>(offs, bsum, cursor, cnt, ghist, bincur, order, N, nb);
    k_csr<<<(E + 255) / 256, 256, 0, stream>>>(heads, rels, tails, cursor, tr, E);
    k_fused<<<ngh, 256, 0, stream>>>(entb, relb, offs, cnt, tr, order, accb, mh, lh, blockmax, N, R);
    k_maxred<<<1, 256, 0, stream>>>(blockmax, Mval, ngh);
    k_gemm_f<<<(N + 127) / 128, 256, 0, stream>>>(entb, accb, mh, lh, Mval, wb, out, N);
}